// Round 5
// baseline (1127.883 us; speedup 1.0000x reference)
//
#include <hip/hip_runtime.h>
#include <hip/hip_bf16.h>
#include <stdint.h>

// non_local_layer: B=8, C=1024, N=48*48=2304, Cb=512.
// R4 post-mortem: inputs ARE f32 (NaN gone when read as f32). Residual 7.64
// error = output written as bf16 into an f32 buffer (ref output dtype is f32:
// packed pairs + zero tail match the observed error exactly). R5: f32 output.
// Internal GEMM compute stays bf16 MFMA (threshold 0.108 ~ 2% of max permits it).

typedef __bf16 bf16;
typedef __attribute__((ext_vector_type(8))) __bf16 bf16x8;
typedef __attribute__((ext_vector_type(4))) float f32x4;

// ---------------- GEMM: 128x128 tile, BK=64, 4 waves x (4x4) 16x16x32 MFMA ----------------
// bt-form: D[m][n] = sum_k A[m][k]*B[n][k]; A:MxK rm, B:NxK rm, D: ld=N, alpha scale.
// LDS: 128 rows x 8 chunks of 16B; chunk (row,s) holds global k-chunk s^(row&7).
template <bool F32OUT>
__global__ __launch_bounds__(256)
void gemm_bt(const bf16* __restrict__ Ag, const bf16* __restrict__ Bg,
             void* __restrict__ Dg, int K, int N, float alpha)
{
    __shared__ char lds[32768];            // A tile 16 KB + B tile 16 KB
    char* ldsA = lds;
    char* ldsB = lds + 16384;

    const int lane = threadIdx.x & 63;
    const int wv   = threadIdx.x >> 6;     // 4 waves, 2x2 arrangement
    const int wm   = wv >> 1;
    const int wn   = wv & 1;

    const bf16* Ab = Ag + (long long)blockIdx.y * 128 * K;
    const bf16* Bb = Bg + (long long)blockIdx.x * 128 * K;

    f32x4 acc[4][4];
    #pragma unroll
    for (int i = 0; i < 4; ++i)
        #pragma unroll
        for (int j = 0; j < 4; ++j) {
            f32x4 z = {0.f, 0.f, 0.f, 0.f};
            acc[i][j] = z;
        }

    for (int k0 = 0; k0 < K; k0 += 64) {
        #pragma unroll
        for (int t = 0; t < 4; ++t) {
            int ch  = (wv * 4 + t) * 64 + lane;   // 0..1023
            int row = ch >> 3;
            int cc  = (ch & 7) ^ (row & 7);
            bf16x8 va = *(const bf16x8*)(Ab + (long long)row * K + k0 + cc * 8);
            bf16x8 vb = *(const bf16x8*)(Bb + (long long)row * K + k0 + cc * 8);
            *(bf16x8*)(ldsA + ch * 16) = va;
            *(bf16x8*)(ldsB + ch * 16) = vb;
        }
        __syncthreads();

        #pragma unroll
        for (int kk = 0; kk < 64; kk += 32) {
            bf16x8 af[4], bfr[4];
            #pragma unroll
            for (int i = 0; i < 4; ++i) {
                int r = wm * 64 + i * 16 + (lane & 15);
                int c = ((kk >> 3) + (lane >> 4)) ^ (r & 7);
                af[i] = *(const bf16x8*)(ldsA + r * 128 + c * 16);
            }
            #pragma unroll
            for (int j = 0; j < 4; ++j) {
                int r = wn * 64 + j * 16 + (lane & 15);
                int c = ((kk >> 3) + (lane >> 4)) ^ (r & 7);
                bfr[j] = *(const bf16x8*)(ldsB + r * 128 + c * 16);
            }
            #pragma unroll
            for (int i = 0; i < 4; ++i)
                #pragma unroll
                for (int j = 0; j < 4; ++j)
                    acc[i][j] = __builtin_amdgcn_mfma_f32_16x16x32_bf16(af[i], bfr[j], acc[i][j], 0, 0, 0);
        }
        __syncthreads();
    }

    // Epilogue: D[row=(lane>>4)*4+t][col=lane&15] per 16x16 tile (verified C/D mapping).
    const int m_base = blockIdx.y * 128 + wm * 64;
    const int n_base = blockIdx.x * 128 + wn * 64;
    #pragma unroll
    for (int i = 0; i < 4; ++i) {
        #pragma unroll
        for (int j = 0; j < 4; ++j) {
            int col = n_base + j * 16 + (lane & 15);
            #pragma unroll
            for (int t = 0; t < 4; ++t) {
                int rowg = m_base + i * 16 + (lane >> 4) * 4 + t;
                float v = acc[i][j][t] * alpha;
                if (F32OUT) ((float*)Dg)[(long long)rowg * N + col] = v;
                else        ((bf16*)Dg)[(long long)rowg * N + col] = (bf16)v;
            }
        }
    }
}

// ---------------- f32 -> bf16 bulk convert (weights) ----------------
__global__ __launch_bounds__(256)
void f32_to_bf16(const float* __restrict__ in, bf16* __restrict__ out, int n)
{
    int idx = (blockIdx.x * 256 + threadIdx.x) * 4;
    if (idx < n) {
        float4 v = *(const float4*)(in + idx);
        out[idx + 0] = (bf16)v.x;
        out[idx + 1] = (bf16)v.y;
        out[idx + 2] = (bf16)v.z;
        out[idx + 3] = (bf16)v.w;
    }
}

// ---------------- per-batch transpose x[C][N] (f32) -> xT[N][C] (bf16) ----------------
__global__ __launch_bounds__(256)
void transpose_f32_bf16(const float* __restrict__ x, bf16* __restrict__ xT)
{
    __shared__ bf16 tile[32][33];
    const int n0 = blockIdx.x * 32;
    const int c0 = blockIdx.y * 32;
    const int tx = threadIdx.x, ty = threadIdx.y;   // (32, 8)
    #pragma unroll
    for (int i = 0; i < 32; i += 8)
        tile[ty + i][tx] = (bf16)x[(long long)(c0 + ty + i) * 2304 + n0 + tx];
    __syncthreads();
    #pragma unroll
    for (int i = 0; i < 32; i += 8)
        xT[(long long)(n0 + ty + i) * 1024 + c0 + tx] = tile[tx][ty + i];
}

// ---------------- row softmax in place (bf16), one block per row ----------------
__global__ __launch_bounds__(256)
void softmax_inplace(bf16* __restrict__ S, int N)
{
    bf16* p = S + (long long)blockIdx.x * N;
    const int tid = threadIdx.x;
    __shared__ float red[256];

    float mx = -1e30f;
    for (int i = tid; i < N; i += 256) mx = fmaxf(mx, (float)p[i]);
    red[tid] = mx; __syncthreads();
    for (int s = 128; s > 0; s >>= 1) { if (tid < s) red[tid] = fmaxf(red[tid], red[tid + s]); __syncthreads(); }
    mx = red[0];
    __syncthreads();

    float sum = 0.f;
    for (int i = tid; i < N; i += 256) {
        float e = __expf((float)p[i] - mx);
        p[i] = (bf16)e;                    // store unnormalized exp
        sum += e;
    }
    red[tid] = sum; __syncthreads();
    for (int s = 128; s > 0; s >>= 1) { if (tid < s) red[tid] += red[tid + s]; __syncthreads(); }
    float inv = 1.0f / red[0];

    for (int i = tid; i < N; i += 256) p[i] = (bf16)((float)p[i] * inv);
}

// ---------------- BN stats: one block per channel, two-pass mean/var (f32 wy) ----------------
__global__ __launch_bounds__(256)
void bn_stats(const float* __restrict__ wy, float* __restrict__ mean, float* __restrict__ istd)
{
    const int c = blockIdx.x;              // 0..1023
    const int tid = threadIdx.x;
    __shared__ float red[256];
    const int NN = 2304;
    const long long CS = 1024LL * 2304;

    float s = 0.f;
    for (int b = 0; b < 8; ++b) {
        const float* p = wy + b * CS + (long long)c * NN;
        for (int i = tid; i < NN; i += 256) s += p[i];
    }
    red[tid] = s; __syncthreads();
    for (int st = 128; st > 0; st >>= 1) { if (tid < st) red[tid] += red[tid + st]; __syncthreads(); }
    float mu = red[0] / 18432.0f;
    __syncthreads();

    float v = 0.f;
    for (int b = 0; b < 8; ++b) {
        const float* p = wy + b * CS + (long long)c * NN;
        for (int i = tid; i < NN; i += 256) { float d = p[i] - mu; v += d * d; }
    }
    red[tid] = v; __syncthreads();
    for (int st = 128; st > 0; st >>= 1) { if (tid < st) red[tid] += red[tid + st]; __syncthreads(); }
    if (tid == 0) {
        mean[c] = mu;
        istd[c] = rsqrtf(red[0] / 18432.0f + 1e-5f);
    }
}

// ---------------- BN apply + residual, all f32, in place on wy(=d_out) ----------------
__global__ __launch_bounds__(256)
void bn_apply(const float* __restrict__ wy, const float* __restrict__ x,
              const float* __restrict__ gamma, const float* __restrict__ beta,
              const float* __restrict__ mean, const float* __restrict__ istd,
              float* __restrict__ z)
{
    long long idx = ((long long)blockIdx.x * 256 + threadIdx.x) * 4;
    int c = (int)((idx / 2304) & 1023);    // layout [B][C][N], N=2304 divisible by 4
    float sc = gamma[c] * istd[c];
    float sh = beta[c] - mean[c] * sc;
    float4 w  = *(const float4*)(wy + idx);
    float4 xv = *(const float4*)(x + idx);
    float4 o;
    o.x = w.x * sc + sh + xv.x;
    o.y = w.y * sc + sh + xv.y;
    o.z = w.z * sc + sh + xv.z;
    o.w = w.w * sc + sh + xv.w;
    *(float4*)(z + idx) = o;
}

extern "C" void kernel_launch(void* const* d_in, const int* in_sizes, int n_in,
                              void* d_out, int out_size, void* d_ws, size_t ws_size,
                              hipStream_t stream)
{
    const float* x     = (const float*)d_in[0];
    const float* Wg    = (const float*)d_in[1];
    const float* Wz    = (const float*)d_in[2];
    const float* gamma = (const float*)d_in[3];
    const float* beta  = (const float*)d_in[4];
    float* zo = (float*)d_out;             // f32 output; also serves as the wy buffer

    const int B = 8, C = 1024, Cb = 512, N = 2304;

    // workspace carve-up: ~22.1 MB total
    char* p = (char*)d_ws;
    auto alloc = [&](size_t bytes) { char* r = p; p += (bytes + 255) & ~(size_t)255; return r; };
    bf16*  Wgb  = (bf16*)alloc((size_t)Cb * C * 2);       // 1.00 MB
    bf16*  Wzb  = (bf16*)alloc((size_t)C * Cb * 2);       // 1.00 MB
    bf16*  xT1  = (bf16*)alloc((size_t)N * C * 2);        // 4.72 MB (one batch)
    bf16*  g1   = (bf16*)alloc((size_t)Cb * N * 2);       // 2.36 MB (one batch)
    bf16*  attn = (bf16*)alloc((size_t)N * N * 2);        // 10.62 MB (one batch)
    bf16*  yT1  = (bf16*)alloc((size_t)N * Cb * 2);       // 2.36 MB (one batch)
    float* mean = (float*)alloc((size_t)C * 4);
    float* istd = (float*)alloc((size_t)C * 4);

    // 0) weights f32 -> bf16
    f32_to_bf16<<<dim3((Cb * C) / (256 * 4)), 256, 0, stream>>>(Wg, Wgb, Cb * C);
    f32_to_bf16<<<dim3((C * Cb) / (256 * 4)), 256, 0, stream>>>(Wz, Wzb, C * Cb);

    // per-batch pipeline, reusing single-batch buffers
    for (int b = 0; b < B; ++b) {
        const float* xb = x + (long long)b * C * N;
        float* wyb = zo + (long long)b * C * N;

        // xT1[n][c] = x[c][n] (bf16)
        transpose_f32_bf16<<<dim3(N / 32, C / 32, 1), dim3(32, 8), 0, stream>>>(xb, xT1);

        // g1[d][n] = sum_c Wgb[d][c] * xT1[n][c]   (M=512, N=2304, K=1024) -> bf16
        gemm_bt<false><<<dim3(N / 128, Cb / 128, 1), 256, 0, stream>>>(Wgb, xT1, g1, C, N, 1.0f);

        // attn[n][m] = sum_c xT1[n][c]*xT1[m][c] / 2304  (M=N=2304, K=1024) -> bf16
        gemm_bt<false><<<dim3(N / 128, N / 128, 1), 256, 0, stream>>>(xT1, xT1, attn, C, N, 1.0f / 2304.0f);

        // softmax over m, in place
        softmax_inplace<<<dim3(N), 256, 0, stream>>>(attn, N);

        // yT1[n][d] = sum_m attn[n][m] * g1[d][m]   (M=2304, N=512, K=2304) -> bf16
        gemm_bt<false><<<dim3(Cb / 128, N / 128, 1), 256, 0, stream>>>(attn, g1, yT1, N, Cb, 1.0f);

        // wyb[c][n] = sum_d Wzb[c][d] * yT1[n][d]    (M=1024, N=2304, K=512) -> f32 into d_out
        gemm_bt<true><<<dim3(N / 128, C / 128, 1), 256, 0, stream>>>(Wzb, yT1, wyb, Cb, N, 1.0f);
    }

    // BN stats over d_out(=wy f32), then apply in place with residual
    bn_stats<<<dim3(C), 256, 0, stream>>>(zo, mean, istd);
    bn_apply<<<dim3((B * C * N) / (256 * 4)), 256, 0, stream>>>(zo, x, gamma, beta, mean, istd, zo);
}

// Round 6
// 458.820 us; speedup vs baseline: 2.4582x; 2.4582x over previous
//
#include <hip/hip_runtime.h>
#include <hip/hip_bf16.h>
#include <stdint.h>

// non_local_layer: B=8, C=1024, N=48*48=2304, Cb=512. f32 in/out, bf16 MFMA inside.
// R5 passed (1128 us). R6: batch everything over blockIdx.z (ws-adaptive chunking),
// register-resident single-pass softmax, single-pass bn stats. GEMM core unchanged.

typedef __bf16 bf16;
typedef __attribute__((ext_vector_type(8))) __bf16 bf16x8;
typedef __attribute__((ext_vector_type(4))) float f32x4;

// ---------------- GEMM: 128x128 tile, BK=64, 4 waves x (4x4) 16x16x32 MFMA ----------------
// bt-form: D[m][n] = sum_k A[m][k]*B[n][k]; per-z strides sA/sB/sD; D ld=N; alpha scale.
// LDS: 128 rows x 8 chunks of 16B; chunk (row,s) holds global k-chunk s^(row&7).
template <bool F32OUT>
__global__ __launch_bounds__(256)
void gemm_bt(const bf16* __restrict__ Ag, const bf16* __restrict__ Bg,
             void* __restrict__ Dg, int K, int N,
             long long sA, long long sB, long long sD, float alpha)
{
    __shared__ char lds[32768];            // A tile 16 KB + B tile 16 KB
    char* ldsA = lds;
    char* ldsB = lds + 16384;

    const int lane = threadIdx.x & 63;
    const int wv   = threadIdx.x >> 6;     // 4 waves, 2x2 arrangement
    const int wm   = wv >> 1;
    const int wn   = wv & 1;

    const bf16* Ab = Ag + (long long)blockIdx.z * sA + (long long)blockIdx.y * 128 * K;
    const bf16* Bb = Bg + (long long)blockIdx.z * sB + (long long)blockIdx.x * 128 * K;

    f32x4 acc[4][4];
    #pragma unroll
    for (int i = 0; i < 4; ++i)
        #pragma unroll
        for (int j = 0; j < 4; ++j) {
            f32x4 z = {0.f, 0.f, 0.f, 0.f};
            acc[i][j] = z;
        }

    for (int k0 = 0; k0 < K; k0 += 64) {
        #pragma unroll
        for (int t = 0; t < 4; ++t) {
            int ch  = (wv * 4 + t) * 64 + lane;   // 0..1023
            int row = ch >> 3;
            int cc  = (ch & 7) ^ (row & 7);
            bf16x8 va = *(const bf16x8*)(Ab + (long long)row * K + k0 + cc * 8);
            bf16x8 vb = *(const bf16x8*)(Bb + (long long)row * K + k0 + cc * 8);
            *(bf16x8*)(ldsA + ch * 16) = va;
            *(bf16x8*)(ldsB + ch * 16) = vb;
        }
        __syncthreads();

        #pragma unroll
        for (int kk = 0; kk < 64; kk += 32) {
            bf16x8 af[4], bfr[4];
            #pragma unroll
            for (int i = 0; i < 4; ++i) {
                int r = wm * 64 + i * 16 + (lane & 15);
                int c = ((kk >> 3) + (lane >> 4)) ^ (r & 7);
                af[i] = *(const bf16x8*)(ldsA + r * 128 + c * 16);
            }
            #pragma unroll
            for (int j = 0; j < 4; ++j) {
                int r = wn * 64 + j * 16 + (lane & 15);
                int c = ((kk >> 3) + (lane >> 4)) ^ (r & 7);
                bfr[j] = *(const bf16x8*)(ldsB + r * 128 + c * 16);
            }
            #pragma unroll
            for (int i = 0; i < 4; ++i)
                #pragma unroll
                for (int j = 0; j < 4; ++j)
                    acc[i][j] = __builtin_amdgcn_mfma_f32_16x16x32_bf16(af[i], bfr[j], acc[i][j], 0, 0, 0);
        }
        __syncthreads();
    }

    // Epilogue: D[row=(lane>>4)*4+t][col=lane&15] per 16x16 tile (verified C/D mapping).
    const int m_base = blockIdx.y * 128 + wm * 64;
    const int n_base = blockIdx.x * 128 + wn * 64;
    #pragma unroll
    for (int i = 0; i < 4; ++i) {
        #pragma unroll
        for (int j = 0; j < 4; ++j) {
            int col = n_base + j * 16 + (lane & 15);
            #pragma unroll
            for (int t = 0; t < 4; ++t) {
                int rowg = m_base + i * 16 + (lane >> 4) * 4 + t;
                float v = acc[i][j][t] * alpha;
                if (F32OUT) ((float*)Dg)[(long long)blockIdx.z * sD + (long long)rowg * N + col] = v;
                else        ((bf16*)Dg)[(long long)blockIdx.z * sD + (long long)rowg * N + col] = (bf16)v;
            }
        }
    }
}

// ---------------- f32 -> bf16 bulk convert (weights) ----------------
__global__ __launch_bounds__(256)
void f32_to_bf16(const float* __restrict__ in, bf16* __restrict__ out, int n)
{
    int idx = (blockIdx.x * 256 + threadIdx.x) * 4;
    if (idx < n) {
        float4 v = *(const float4*)(in + idx);
        out[idx + 0] = (bf16)v.x;
        out[idx + 1] = (bf16)v.y;
        out[idx + 2] = (bf16)v.z;
        out[idx + 3] = (bf16)v.w;
    }
}

// ---------------- batched transpose x[z][C][N] (f32) -> xT[z][N][C] (bf16) ----------------
__global__ __launch_bounds__(256)
void transpose_f32_bf16(const float* __restrict__ x, bf16* __restrict__ xT)
{
    __shared__ bf16 tile[32][33];
    const float* xb = x + (long long)blockIdx.z * 1024 * 2304;
    bf16* xo = xT + (long long)blockIdx.z * 2304 * 1024;
    const int n0 = blockIdx.x * 32;
    const int c0 = blockIdx.y * 32;
    const int tx = threadIdx.x, ty = threadIdx.y;   // (32, 8)
    #pragma unroll
    for (int i = 0; i < 32; i += 8)
        tile[ty + i][tx] = (bf16)xb[(long long)(c0 + ty + i) * 2304 + n0 + tx];
    __syncthreads();
    #pragma unroll
    for (int i = 0; i < 32; i += 8)
        xo[(long long)(n0 + ty + i) * 1024 + c0 + tx] = tile[tx][ty + i];
}

// ---------------- register-resident row softmax (N=2304), one block per row ----------------
// thread t owns bf16x8 at t*8 (0..2047) plus scalar at 2048+t. One read, one write.
__global__ __launch_bounds__(256)
void softmax_rows(bf16* __restrict__ S)
{
    bf16* p = S + (long long)blockIdx.x * 2304;
    const int t = threadIdx.x;
    __shared__ float red[256];

    bf16x8 v8 = *(const bf16x8*)(p + t * 8);
    float vt = (float)p[2048 + t];
    float f[8];
    float mx = vt;
    #pragma unroll
    for (int i = 0; i < 8; ++i) { f[i] = (float)v8[i]; mx = fmaxf(mx, f[i]); }

    red[t] = mx; __syncthreads();
    for (int s = 128; s > 0; s >>= 1) { if (t < s) red[t] = fmaxf(red[t], red[t + s]); __syncthreads(); }
    mx = red[0];
    __syncthreads();

    float sum = 0.f;
    #pragma unroll
    for (int i = 0; i < 8; ++i) { f[i] = __expf(f[i] - mx); sum += f[i]; }
    vt = __expf(vt - mx); sum += vt;

    red[t] = sum; __syncthreads();
    for (int s = 128; s > 0; s >>= 1) { if (t < s) red[t] += red[t + s]; __syncthreads(); }
    float inv = 1.0f / red[0];

    bf16x8 o;
    #pragma unroll
    for (int i = 0; i < 8; ++i) o[i] = (bf16)(f[i] * inv);
    *(bf16x8*)(p + t * 8) = o;
    p[2048 + t] = (bf16)(vt * inv);
}

// ---------------- BN partial sums: one block per (batch, channel), single pass ----------------
__global__ __launch_bounds__(256)
void bn_partial(const float* __restrict__ wy, float* __restrict__ ps, float* __restrict__ pq)
{
    const int b = blockIdx.x, c = blockIdx.y, t = threadIdx.x;
    const float* p = wy + ((long long)b * 1024 + c) * 2304;
    float s = 0.f, q = 0.f;
    for (int i = t * 4; i < 2304; i += 1024) {
        float4 v = *(const float4*)(p + i);
        s += v.x + v.y + v.z + v.w;
        q += v.x * v.x + v.y * v.y + v.z * v.z + v.w * v.w;
    }
    __shared__ float rs[256], rq[256];
    rs[t] = s; rq[t] = q; __syncthreads();
    for (int st = 128; st > 0; st >>= 1) {
        if (t < st) { rs[t] += rs[t + st]; rq[t] += rq[t + st]; }
        __syncthreads();
    }
    if (t == 0) { ps[b * 1024 + c] = rs[0]; pq[b * 1024 + c] = rq[0]; }
}

__global__ __launch_bounds__(256)
void bn_finalize(const float* __restrict__ ps, const float* __restrict__ pq,
                 float* __restrict__ mean, float* __restrict__ istd)
{
    int c = blockIdx.x * 256 + threadIdx.x;   // grid 4 x 256 = 1024
    float s = 0.f, q = 0.f;
    #pragma unroll
    for (int b = 0; b < 8; ++b) { s += ps[b * 1024 + c]; q += pq[b * 1024 + c]; }
    float mu = s / 18432.0f;
    mean[c] = mu;
    istd[c] = rsqrtf(q / 18432.0f - mu * mu + 1e-5f);
}

// ---------------- BN apply + residual, all f32, in place on wy(=d_out) ----------------
__global__ __launch_bounds__(256)
void bn_apply(const float* __restrict__ wy, const float* __restrict__ x,
              const float* __restrict__ gamma, const float* __restrict__ beta,
              const float* __restrict__ mean, const float* __restrict__ istd,
              float* __restrict__ z)
{
    long long idx = ((long long)blockIdx.x * 256 + threadIdx.x) * 4;
    int c = (int)((idx / 2304) & 1023);    // layout [B][C][N], N divisible by 4
    float sc = gamma[c] * istd[c];
    float sh = beta[c] - mean[c] * sc;
    float4 w  = *(const float4*)(wy + idx);
    float4 xv = *(const float4*)(x + idx);
    float4 o;
    o.x = w.x * sc + sh + xv.x;
    o.y = w.y * sc + sh + xv.y;
    o.z = w.z * sc + sh + xv.z;
    o.w = w.w * sc + sh + xv.w;
    *(float4*)(z + idx) = o;
}

extern "C" void kernel_launch(void* const* d_in, const int* in_sizes, int n_in,
                              void* d_out, int out_size, void* d_ws, size_t ws_size,
                              hipStream_t stream)
{
    const float* x     = (const float*)d_in[0];
    const float* Wg    = (const float*)d_in[1];
    const float* Wz    = (const float*)d_in[2];
    const float* gamma = (const float*)d_in[3];
    const float* beta  = (const float*)d_in[4];
    float* zo = (float*)d_out;             // f32 output; also serves as the wy buffer

    const int B = 8, C = 1024, Cb = 512, N = 2304;

    // ws-adaptive batch chunking: BC in {8,4,2,1}, largest whose footprint fits.
    const size_t fixedB = ((size_t)Cb * C * 2) * 2 + (size_t)8 * C * 4 * 2 + (size_t)C * 4 * 2 + 4096;
    const size_t perB   = ((size_t)N * C + (size_t)Cb * N + (size_t)N * N + (size_t)N * Cb) * 2 + 1024;
    int BC = 8;
    while (BC > 1 && fixedB + perB * (size_t)BC > ws_size) BC >>= 1;

    char* p = (char*)d_ws;
    auto alloc = [&](size_t bytes) { char* r = p; p += (bytes + 255) & ~(size_t)255; return r; };
    bf16*  Wgb  = (bf16*)alloc((size_t)Cb * C * 2);
    bf16*  Wzb  = (bf16*)alloc((size_t)C * Cb * 2);
    float* psum = (float*)alloc((size_t)8 * C * 4);
    float* pqsm = (float*)alloc((size_t)8 * C * 4);
    float* mean = (float*)alloc((size_t)C * 4);
    float* istd = (float*)alloc((size_t)C * 4);
    bf16*  xT   = (bf16*)alloc((size_t)BC * N * C * 2);
    bf16*  g    = (bf16*)alloc((size_t)BC * Cb * N * 2);
    bf16*  attn = (bf16*)alloc((size_t)BC * N * N * 2);
    bf16*  yT   = (bf16*)alloc((size_t)BC * N * Cb * 2);

    // 0) weights f32 -> bf16
    f32_to_bf16<<<dim3((Cb * C) / (256 * 4)), 256, 0, stream>>>(Wg, Wgb, Cb * C);
    f32_to_bf16<<<dim3((C * Cb) / (256 * 4)), 256, 0, stream>>>(Wz, Wzb, C * Cb);

    for (int cs = 0; cs < B; cs += BC) {
        const float* xc = x + (long long)cs * C * N;
        float* wyc = zo + (long long)cs * C * N;

        // xT[z][n][c] = x[cs+z][c][n] (bf16)
        transpose_f32_bf16<<<dim3(N / 32, C / 32, BC), dim3(32, 8), 0, stream>>>(xc, xT);

        // g[z][d][n] = sum_c Wgb[d][c] * xT[z][n][c]   (M=512, N=2304, K=1024)
        gemm_bt<false><<<dim3(N / 128, Cb / 128, BC), 256, 0, stream>>>(
            Wgb, xT, g, C, N, 0, (long long)N * C, (long long)Cb * N, 1.0f);

        // attn[z][n][m] = sum_c xT[z][n][c]*xT[z][m][c] / 2304  (M=N=2304, K=1024)
        gemm_bt<false><<<dim3(N / 128, N / 128, BC), 256, 0, stream>>>(
            xT, xT, attn, C, N, (long long)N * C, (long long)N * C, (long long)N * N, 1.0f / 2304.0f);

        // row softmax, one read one write
        softmax_rows<<<dim3(BC * N), 256, 0, stream>>>(attn);

        // yT[z][n][d] = sum_m attn[z][n][m] * g[z][d][m]  (M=2304, N=512, K=2304)
        gemm_bt<false><<<dim3(Cb / 128, N / 128, BC), 256, 0, stream>>>(
            attn, g, yT, N, Cb, (long long)N * N, (long long)Cb * N, (long long)N * Cb, 1.0f);

        // wy[cs+z][c][n] = sum_d Wzb[c][d] * yT[z][n][d]  (M=1024, N=2304, K=512) -> f32 d_out
        gemm_bt<true><<<dim3(N / 128, C / 128, BC), 256, 0, stream>>>(
            Wzb, yT, wyc, Cb, N, 0, (long long)N * Cb, (long long)C * N, 1.0f);
    }

    // BN: single-pass partials -> finalize -> apply (+residual)
    bn_partial<<<dim3(B, C), 256, 0, stream>>>(zo, psum, pqsm);
    bn_finalize<<<dim3(C / 256), 256, 0, stream>>>(psum, pqsm, mean, istd);
    bn_apply<<<dim3((B * C * N) / (256 * 4)), 256, 0, stream>>>(zo, x, gamma, beta, mean, istd, zo);
}

// Round 8
// 447.163 us; speedup vs baseline: 2.5223x; 1.0261x over previous
//
#include <hip/hip_runtime.h>
#include <hip/hip_bf16.h>
#include <stdint.h>

// non_local_layer: B=8, C=1024, N=48*48=2304, Cb=512. f32 in/out, bf16 MFMA inside.
// R7 post-mortem: launch#1 correct, later launches deterministically wrong (4.625
// finite). gamma=0 masks all GEMM/BN values; only a cross-launch state perturbation
// fits -> prime suspect is the async global_load_lds staging (M0/addrspace-cast
// blast radius unbounded from source). R8: revert staging to R6's proven manual
// bf16x8 path; KEEP the fused-BN epilogue (provably in-bounds). Pure bisection.

typedef __bf16 bf16;
typedef __attribute__((ext_vector_type(8))) __bf16 bf16x8;
typedef __attribute__((ext_vector_type(4))) float f32x4;

// ---------------- GEMM: 128x128 tile, BK=64, 4 waves x (4x4) 16x16x32 MFMA ----------------
// bt-form: D[m][n] = sum_k A[m][k]*B[n][k]; per-z strides sA/sB/sD; D ld=N; alpha scale.
// LDS: 128 rows x 8 chunks of 16B; chunk (row,s) holds global k-chunk s^(row&7).
// BNRED: accumulate sum/sumsq of D over columns (n) per row (channel) into ps/pq.
template <bool F32OUT, bool BNRED>
__global__ __launch_bounds__(256)
void gemm_bt(const bf16* __restrict__ Ag, const bf16* __restrict__ Bg,
             void* __restrict__ Dg, int K, int N,
             long long sA, long long sB, long long sD, float alpha,
             float* __restrict__ ps, float* __restrict__ pq)
{
    __shared__ char lds[32768];            // A tile 16 KB + B tile 16 KB
    char* ldsA = lds;
    char* ldsB = lds + 16384;

    const int lane = threadIdx.x & 63;
    const int wv   = threadIdx.x >> 6;     // 4 waves, 2x2 arrangement
    const int wm   = wv >> 1;
    const int wn   = wv & 1;

    const bf16* Ab = Ag + (long long)blockIdx.z * sA + (long long)blockIdx.y * 128 * K;
    const bf16* Bb = Bg + (long long)blockIdx.z * sB + (long long)blockIdx.x * 128 * K;

    f32x4 acc[4][4];
    #pragma unroll
    for (int i = 0; i < 4; ++i)
        #pragma unroll
        for (int j = 0; j < 4; ++j) {
            f32x4 z = {0.f, 0.f, 0.f, 0.f};
            acc[i][j] = z;
        }

    for (int k0 = 0; k0 < K; k0 += 64) {
        // Manual staging (R6-proven): each thread moves one 16B chunk of A and B per t.
        #pragma unroll
        for (int t = 0; t < 4; ++t) {
            int ch  = (wv * 4 + t) * 64 + lane;   // 0..1023
            int row = ch >> 3;
            int cc  = (ch & 7) ^ (row & 7);
            bf16x8 va = *(const bf16x8*)(Ab + (long long)row * K + k0 + cc * 8);
            bf16x8 vb = *(const bf16x8*)(Bb + (long long)row * K + k0 + cc * 8);
            *(bf16x8*)(ldsA + ch * 16) = va;
            *(bf16x8*)(ldsB + ch * 16) = vb;
        }
        __syncthreads();

        #pragma unroll
        for (int kk = 0; kk < 64; kk += 32) {
            bf16x8 af[4], bfr[4];
            #pragma unroll
            for (int i = 0; i < 4; ++i) {
                int r = wm * 64 + i * 16 + (lane & 15);
                int c = ((kk >> 3) + (lane >> 4)) ^ (r & 7);
                af[i] = *(const bf16x8*)(ldsA + r * 128 + c * 16);
            }
            #pragma unroll
            for (int j = 0; j < 4; ++j) {
                int r = wn * 64 + j * 16 + (lane & 15);
                int c = ((kk >> 3) + (lane >> 4)) ^ (r & 7);
                bfr[j] = *(const bf16x8*)(ldsB + r * 128 + c * 16);
            }
            #pragma unroll
            for (int i = 0; i < 4; ++i)
                #pragma unroll
                for (int j = 0; j < 4; ++j)
                    acc[i][j] = __builtin_amdgcn_mfma_f32_16x16x32_bf16(af[i], bfr[j], acc[i][j], 0, 0, 0);
        }
        __syncthreads();
    }

    // Repurpose LDS for the BN reduction scratch (k-loop ended with a barrier).
    float* bs = (float*)lds;               // [128] per-channel sum
    float* bq = (float*)(lds + 512);       // [128] per-channel sumsq
    if (BNRED) {
        if (threadIdx.x < 128) { bs[threadIdx.x] = 0.f; bq[threadIdx.x] = 0.f; }
        __syncthreads();
    }

    // Epilogue: D[row=(lane>>4)*4+t][col=lane&15] per 16x16 tile (verified C/D mapping).
    const int m_base = blockIdx.y * 128 + wm * 64;
    const int n_base = blockIdx.x * 128 + wn * 64;
    float s_it[4][4], q_it[4][4];
    #pragma unroll
    for (int i = 0; i < 4; ++i) {
        #pragma unroll
        for (int t = 0; t < 4; ++t) { s_it[i][t] = 0.f; q_it[i][t] = 0.f; }
    }
    #pragma unroll
    for (int i = 0; i < 4; ++i) {
        #pragma unroll
        for (int j = 0; j < 4; ++j) {
            int col = n_base + j * 16 + (lane & 15);
            #pragma unroll
            for (int t = 0; t < 4; ++t) {
                int rowg = m_base + i * 16 + (lane >> 4) * 4 + t;
                float v = acc[i][j][t] * alpha;
                if (F32OUT) ((float*)Dg)[(long long)blockIdx.z * sD + (long long)rowg * N + col] = v;
                else        ((bf16*)Dg)[(long long)blockIdx.z * sD + (long long)rowg * N + col] = (bf16)v;
                if (BNRED) { s_it[i][t] += v; q_it[i][t] += v * v; }
            }
        }
    }

    if (BNRED) {
        // reduce across the 16 lanes of each quad (they hold the same channel row)
        #pragma unroll
        for (int i = 0; i < 4; ++i) {
            #pragma unroll
            for (int t = 0; t < 4; ++t) {
                float s = s_it[i][t], q = q_it[i][t];
                #pragma unroll
                for (int m = 1; m < 16; m <<= 1) {
                    s += __shfl_xor(s, m);
                    q += __shfl_xor(q, m);
                }
                if ((lane & 15) == 0) {
                    int cl = wm * 64 + i * 16 + (lane >> 4) * 4 + t;   // 0..127
                    atomicAdd(&bs[cl], s);
                    atomicAdd(&bq[cl], q);
                }
            }
        }
        __syncthreads();
        if (threadIdx.x < 128) {
            int cg = blockIdx.y * 128 + threadIdx.x;
            atomicAdd(&ps[cg], bs[threadIdx.x]);
            atomicAdd(&pq[cg], bq[threadIdx.x]);
        }
    }
}

// ---------------- f32 -> bf16 bulk convert (weights) ----------------
__global__ __launch_bounds__(256)
void f32_to_bf16(const float* __restrict__ in, bf16* __restrict__ out, int n)
{
    int idx = (blockIdx.x * 256 + threadIdx.x) * 4;
    if (idx < n) {
        float4 v = *(const float4*)(in + idx);
        out[idx + 0] = (bf16)v.x;
        out[idx + 1] = (bf16)v.y;
        out[idx + 2] = (bf16)v.z;
        out[idx + 3] = (bf16)v.w;
    }
}

// ---------------- zero-init BN accumulators (ws is poisoned 0xAA every launch) ----------------
__global__ __launch_bounds__(256)
void zero_f32(float* __restrict__ p)
{
    p[blockIdx.x * 256 + threadIdx.x] = 0.f;
}

// ---------------- batched transpose x[z][C][N] (f32) -> xT[z][N][C] (bf16) ----------------
__global__ __launch_bounds__(256)
void transpose_f32_bf16(const float* __restrict__ x, bf16* __restrict__ xT)
{
    __shared__ bf16 tile[32][33];
    const float* xb = x + (long long)blockIdx.z * 1024 * 2304;
    bf16* xo = xT + (long long)blockIdx.z * 2304 * 1024;
    const int n0 = blockIdx.x * 32;
    const int c0 = blockIdx.y * 32;
    const int tx = threadIdx.x, ty = threadIdx.y;   // (32, 8)
    #pragma unroll
    for (int i = 0; i < 32; i += 8)
        tile[ty + i][tx] = (bf16)xb[(long long)(c0 + ty + i) * 2304 + n0 + tx];
    __syncthreads();
    #pragma unroll
    for (int i = 0; i < 32; i += 8)
        xo[(long long)(n0 + ty + i) * 1024 + c0 + tx] = tile[tx][ty + i];
}

// ---------------- register-resident row softmax (N=2304), one block per row ----------------
__global__ __launch_bounds__(256)
void softmax_rows(bf16* __restrict__ S)
{
    bf16* p = S + (long long)blockIdx.x * 2304;
    const int t = threadIdx.x;
    __shared__ float red[256];

    bf16x8 v8 = *(const bf16x8*)(p + t * 8);
    float vt = (float)p[2048 + t];
    float f[8];
    float mx = vt;
    #pragma unroll
    for (int i = 0; i < 8; ++i) { f[i] = (float)v8[i]; mx = fmaxf(mx, f[i]); }

    red[t] = mx; __syncthreads();
    for (int s = 128; s > 0; s >>= 1) { if (t < s) red[t] = fmaxf(red[t], red[t + s]); __syncthreads(); }
    mx = red[0];
    __syncthreads();

    float sum = 0.f;
    #pragma unroll
    for (int i = 0; i < 8; ++i) { f[i] = __expf(f[i] - mx); sum += f[i]; }
    vt = __expf(vt - mx); sum += vt;

    red[t] = sum; __syncthreads();
    for (int s = 128; s > 0; s >>= 1) { if (t < s) red[t] += red[t + s]; __syncthreads(); }
    float inv = 1.0f / red[0];

    bf16x8 o;
    #pragma unroll
    for (int i = 0; i < 8; ++i) o[i] = (bf16)(f[i] * inv);
    *(bf16x8*)(p + t * 8) = o;
    p[2048 + t] = (bf16)(vt * inv);
}

// ---------------- BN finalize: psum/pqsm already summed over all batches ----------------
__global__ __launch_bounds__(256)
void bn_finalize(const float* __restrict__ ps, const float* __restrict__ pq,
                 float* __restrict__ mean, float* __restrict__ istd)
{
    int c = blockIdx.x * 256 + threadIdx.x;   // grid 4 x 256 = 1024
    float mu = ps[c] / 18432.0f;
    mean[c] = mu;
    istd[c] = rsqrtf(pq[c] / 18432.0f - mu * mu + 1e-5f);
}

// ---------------- BN apply + residual, all f32, in place on wy(=d_out) ----------------
__global__ __launch_bounds__(256)
void bn_apply(const float* __restrict__ wy, const float* __restrict__ x,
              const float* __restrict__ gamma, const float* __restrict__ beta,
              const float* __restrict__ mean, const float* __restrict__ istd,
              float* __restrict__ z)
{
    long long idx = ((long long)blockIdx.x * 256 + threadIdx.x) * 4;
    int c = (int)((idx / 2304) & 1023);    // layout [B][C][N], N divisible by 4
    float sc = gamma[c] * istd[c];
    float sh = beta[c] - mean[c] * sc;
    float4 w  = *(const float4*)(wy + idx);
    float4 xv = *(const float4*)(x + idx);
    float4 o;
    o.x = w.x * sc + sh + xv.x;
    o.y = w.y * sc + sh + xv.y;
    o.z = w.z * sc + sh + xv.z;
    o.w = w.w * sc + sh + xv.w;
    *(float4*)(z + idx) = o;
}

extern "C" void kernel_launch(void* const* d_in, const int* in_sizes, int n_in,
                              void* d_out, int out_size, void* d_ws, size_t ws_size,
                              hipStream_t stream)
{
    const float* x     = (const float*)d_in[0];
    const float* Wg    = (const float*)d_in[1];
    const float* Wz    = (const float*)d_in[2];
    const float* gamma = (const float*)d_in[3];
    const float* beta  = (const float*)d_in[4];
    float* zo = (float*)d_out;             // f32 output; also serves as the wy buffer

    const int B = 8, C = 1024, Cb = 512, N = 2304;

    // ws-adaptive batch chunking: BC in {8,4,2,1}, largest whose footprint fits.
    const size_t fixedB = ((size_t)Cb * C * 2) * 2 + (size_t)C * 4 * 4 + 4096;
    const size_t perB   = ((size_t)N * C + (size_t)Cb * N + (size_t)N * N + (size_t)N * Cb) * 2 + 1024;
    int BC = 8;
    while (BC > 1 && fixedB + perB * (size_t)BC > ws_size) BC >>= 1;

    char* p = (char*)d_ws;
    auto alloc = [&](size_t bytes) { char* r = p; p += (bytes + 255) & ~(size_t)255; return r; };
    bf16*  Wgb  = (bf16*)alloc((size_t)Cb * C * 2);
    bf16*  Wzb  = (bf16*)alloc((size_t)C * Cb * 2);
    float* psum = (float*)alloc((size_t)C * 4);   // contiguous with pqsm (both 4 KB)
    float* pqsm = (float*)alloc((size_t)C * 4);
    float* mean = (float*)alloc((size_t)C * 4);
    float* istd = (float*)alloc((size_t)C * 4);
    bf16*  xT   = (bf16*)alloc((size_t)BC * N * C * 2);
    bf16*  g    = (bf16*)alloc((size_t)BC * Cb * N * 2);
    bf16*  attn = (bf16*)alloc((size_t)BC * N * N * 2);
    bf16*  yT   = (bf16*)alloc((size_t)BC * N * Cb * 2);

    // 0) weights f32 -> bf16; zero BN accumulators (psum+pqsm contiguous, 2048 floats)
    f32_to_bf16<<<dim3((Cb * C) / (256 * 4)), 256, 0, stream>>>(Wg, Wgb, Cb * C);
    f32_to_bf16<<<dim3((C * Cb) / (256 * 4)), 256, 0, stream>>>(Wz, Wzb, C * Cb);
    zero_f32<<<dim3(8), 256, 0, stream>>>(psum);

    for (int cs = 0; cs < B; cs += BC) {
        const float* xc = x + (long long)cs * C * N;
        float* wyc = zo + (long long)cs * C * N;

        // xT[z][n][c] = x[cs+z][c][n] (bf16)
        transpose_f32_bf16<<<dim3(N / 32, C / 32, BC), dim3(32, 8), 0, stream>>>(xc, xT);

        // g[z][d][n] = sum_c Wgb[d][c] * xT[z][n][c]   (M=512, N=2304, K=1024)
        gemm_bt<false, false><<<dim3(N / 128, Cb / 128, BC), 256, 0, stream>>>(
            Wgb, xT, g, C, N, 0, (long long)N * C, (long long)Cb * N, 1.0f, nullptr, nullptr);

        // attn[z][n][m] = sum_c xT[z][n][c]*xT[z][m][c] / 2304  (M=N=2304, K=1024)
        gemm_bt<false, false><<<dim3(N / 128, N / 128, BC), 256, 0, stream>>>(
            xT, xT, attn, C, N, (long long)N * C, (long long)N * C, (long long)N * N, 1.0f / 2304.0f,
            nullptr, nullptr);

        // row softmax, one read one write
        softmax_rows<<<dim3(BC * N), 256, 0, stream>>>(attn);

        // yT[z][n][d] = sum_m attn[z][n][m] * g[z][d][m]  (M=2304, N=512, K=2304)
        gemm_bt<false, false><<<dim3(Cb / 128, N / 128, BC), 256, 0, stream>>>(
            attn, g, yT, N, Cb, (long long)N * N, (long long)Cb * N, (long long)N * Cb, 1.0f,
            nullptr, nullptr);

        // wy[cs+z][c][n] = sum_d Wzb[c][d] * yT[z][n][d]  (M=1024, N=2304, K=512)
        // -> f32 into d_out, with fused BN sum/sumsq accumulation
        gemm_bt<true, true><<<dim3(N / 128, C / 128, BC), 256, 0, stream>>>(
            Wzb, yT, wyc, Cb, N, 0, (long long)N * Cb, (long long)C * N, 1.0f, psum, pqsm);
    }

    // BN: finalize -> apply (+residual)
    bn_finalize<<<dim3(C / 256), 256, 0, stream>>>(psum, pqsm, mean, istd);
    bn_apply<<<dim3((B * C * N) / (256 * 4)), 256, 0, stream>>>(zo, x, gamma, beta, mean, istd, zo);
}